// Round 5
// baseline (541.971 us; speedup 1.0000x reference)
//
#include <hip/hip_runtime.h>

// GraphSAGE 3-layer, N=50000, E=800000, D=128, D_OUT=64, fp32.
// R5: GEMM 8x8 register tile (256 FMA : 16 ds_read_b128 per k4 -> VALU-bound),
//     K-chunk 32, LDS stride 36; gather: slot=node, 2 nodes/wave, unroll 4.

#define D 128
#define K2 256

// ---------- CSR build ----------
__global__ void hist_kernel(const int* __restrict__ row, int* __restrict__ cnt, int E) {
    int e = blockIdx.x * blockDim.x + threadIdx.x;
    if (e < E) atomicAdd(&cnt[row[e]], 1);
}

__global__ void scan1_kernel(const int* __restrict__ cnt, int* __restrict__ rowptr,
                             int* __restrict__ bsum, int N) {
    __shared__ int s[256];
    int tid = threadIdx.x;
    int gid = blockIdx.x * 256 + tid;
    int v = (gid < N) ? cnt[gid] : 0;
    s[tid] = v;
    __syncthreads();
    for (int off = 1; off < 256; off <<= 1) {
        int t = (tid >= off) ? s[tid - off] : 0;
        __syncthreads();
        s[tid] += t;
        __syncthreads();
    }
    if (gid < N) rowptr[gid] = s[tid] - v;
    if (tid == 255) bsum[blockIdx.x] = s[255];
}

__global__ void scan2_kernel(int* __restrict__ bsum, int* __restrict__ boff, int nb) {
    __shared__ int s[256];
    int tid = threadIdx.x;
    int v = (tid < nb) ? bsum[tid] : 0;
    s[tid] = v;
    __syncthreads();
    for (int off = 1; off < 256; off <<= 1) {
        int t = (tid >= off) ? s[tid - off] : 0;
        __syncthreads();
        s[tid] += t;
        __syncthreads();
    }
    if (tid < nb) boff[tid] = s[tid] - v;
}

__global__ void scan3_kernel(int* __restrict__ rowptr, const int* __restrict__ boff,
                             int* __restrict__ cursor, int N, int E) {
    int gid = blockIdx.x * 256 + threadIdx.x;
    if (gid < N) {
        int v = rowptr[gid] + boff[gid >> 8];
        rowptr[gid] = v;
        cursor[gid] = v;
    } else if (gid == N) {
        rowptr[N] = E;
    }
}

__global__ void scatter_kernel(const int* __restrict__ row, const int* __restrict__ col,
                               const float* __restrict__ ew, int* __restrict__ cursor,
                               int2* __restrict__ ep, int E) {
    int e = blockIdx.x * blockDim.x + threadIdx.x;
    if (e >= E) return;
    int p = atomicAdd(&cursor[row[e]], 1);
    ep[p] = make_int2(col[e], __float_as_int(ew[e]));
}

// ---------- gather aggregation ----------
// One wave per 2 nodes: slot (32 lanes) = node; each slot walks its own edge
// list with unroll x4 -> 8 gathers in flight per wave. float4/lane covers the
// 128-float row. Writes agg pre-divided by clipped degree.
__global__ void gather_agg(const float* __restrict__ src, const int* __restrict__ rowptr,
                           const int2* __restrict__ ep, float* __restrict__ agg, int N) {
    long long t = (long long)blockIdx.x * blockDim.x + threadIdx.x;
    int wid = (int)(t >> 6);
    int lane = threadIdx.x & 63;
    int slot = lane >> 5;
    int fl = lane & 31;
    int n = wid * 2 + slot;
    if (n >= N) return;
    int beg = rowptr[n], end = rowptr[n + 1];
    float4 acc = make_float4(0.f, 0.f, 0.f, 0.f);
    float ds = 0.f;
    int e = beg;
    for (; e + 3 < end; e += 4) {
        int2 p0 = ep[e];
        int2 p1 = ep[e + 1];
        int2 p2 = ep[e + 2];
        int2 p3 = ep[e + 3];
        float w0 = __int_as_float(p0.y), w1 = __int_as_float(p1.y);
        float w2 = __int_as_float(p2.y), w3 = __int_as_float(p3.y);
        float4 v0 = *reinterpret_cast<const float4*>(src + (size_t)p0.x * D + fl * 4);
        float4 v1 = *reinterpret_cast<const float4*>(src + (size_t)p1.x * D + fl * 4);
        float4 v2 = *reinterpret_cast<const float4*>(src + (size_t)p2.x * D + fl * 4);
        float4 v3 = *reinterpret_cast<const float4*>(src + (size_t)p3.x * D + fl * 4);
        acc.x += v0.x * w0 + v1.x * w1 + v2.x * w2 + v3.x * w3;
        acc.y += v0.y * w0 + v1.y * w1 + v2.y * w2 + v3.y * w3;
        acc.z += v0.z * w0 + v1.z * w1 + v2.z * w2 + v3.z * w3;
        acc.w += v0.w * w0 + v1.w * w1 + v2.w * w2 + v3.w * w3;
        ds += w0 + w1 + w2 + w3;
    }
    for (; e < end; ++e) {
        int2 p = ep[e];
        float w = __int_as_float(p.y);
        float4 v = *reinterpret_cast<const float4*>(src + (size_t)p.x * D + fl * 4);
        acc.x += v.x * w; acc.y += v.y * w; acc.z += v.z * w; acc.w += v.w * w;
        ds += w;
    }
    float inv = 1.0f / (ds > 1.f ? ds : 1.f);
    float4 o = make_float4(acc.x * inv, acc.y * inv, acc.z * inv, acc.w * inv);
    *reinterpret_cast<float4*>(agg + (size_t)n * D + fl * 4) = o;
}

// ---------- tiled GEMM: C[N,OUT] = [x|agg] @ W^T + b ----------
// Block 256 threads (tx=tid&15, ty=tid>>4). Tile: 128 nodes x OUT cols.
// Thread: nodes {ty+16i, i<8} x cols {tx+16j, j<JC}. K in 8 chunks of 32.
// LDS stride 36 (=4 mod 32): h-reads 4-addr broadcast, w-reads 2-way -> free.
template<int OUT, bool RELU>
__global__ __launch_bounds__(256) void sage_linear(
    const float* __restrict__ xin, const float* __restrict__ agg,
    const float* __restrict__ W, const float* __restrict__ bias,
    float* __restrict__ out, int N) {
    constexpr int JC = OUT / 16;          // cols per thread (8 or 4)
    constexpr int NT = 8;                 // nodes per thread
    constexpr int KC = 32;                // K chunk
    constexpr int LDW = KC + 4;           // 36
    __shared__ float hs[128][LDW];
    __shared__ float ws[OUT][LDW];
    int tid = threadIdx.x;
    int tx = tid & 15, ty = tid >> 4;
    int n0 = blockIdx.x * 128;
    float acc[NT][JC];
#pragma unroll
    for (int i = 0; i < NT; i++)
#pragma unroll
        for (int j = 0; j < JC; j++) acc[i][j] = 0.f;

    for (int kc = 0; kc < K2; kc += KC) {
        const float* src = (kc < D) ? xin : agg;
        int cb = kc & (D - 1);
        // stage H chunk: 128 rows x 8 float4 (4 per thread)
        for (int s = tid; s < 128 * (KC / 4); s += 256) {
            int r = s >> 3, f4 = s & 7;
            int n = n0 + r;
            float4 v = make_float4(0.f, 0.f, 0.f, 0.f);
            if (n < N) v = *reinterpret_cast<const float4*>(src + (size_t)n * D + cb + f4 * 4);
            *reinterpret_cast<float4*>(&hs[r][f4 * 4]) = v;
        }
        // stage W chunk: OUT rows x 8 float4
        for (int s = tid; s < OUT * (KC / 4); s += 256) {
            int r = s >> 3, f4 = s & 7;
            *reinterpret_cast<float4*>(&ws[r][f4 * 4]) =
                *reinterpret_cast<const float4*>(W + (size_t)r * K2 + kc + f4 * 4);
        }
        __syncthreads();
        for (int k4 = 0; k4 < KC / 4; ++k4) {
            float4 h4[NT];
            float4 w4[JC];
#pragma unroll
            for (int i = 0; i < NT; i++) h4[i] = *reinterpret_cast<float4*>(&hs[ty + 16 * i][k4 * 4]);
#pragma unroll
            for (int j = 0; j < JC; j++) w4[j] = *reinterpret_cast<float4*>(&ws[tx + 16 * j][k4 * 4]);
#pragma unroll
            for (int j = 0; j < JC; j++)
#pragma unroll
                for (int i = 0; i < NT; i++)
                    acc[i][j] += h4[i].x * w4[j].x + h4[i].y * w4[j].y +
                                 h4[i].z * w4[j].z + h4[i].w * w4[j].w;
        }
        __syncthreads();
    }
#pragma unroll
    for (int j = 0; j < JC; j++) {
        int colj = tx + 16 * j;
        float bb = bias[colj];
#pragma unroll
        for (int i = 0; i < NT; i++) {
            int n = n0 + ty + 16 * i;
            if (n < N) {
                float y = acc[i][j] + bb;
                if (RELU) y = y > 0.f ? y : 0.f;
                out[(size_t)n * OUT + colj] = y;
            }
        }
    }
}

extern "C" void kernel_launch(void* const* d_in, const int* in_sizes, int n_in,
                              void* d_out, int out_size, void* d_ws, size_t ws_size,
                              hipStream_t stream) {
    const float* x  = (const float*)d_in[0];
    const int*   ei = (const int*)d_in[1];
    const float* ew = (const float*)d_in[2];
    const float* W0 = (const float*)d_in[3];
    const float* b0 = (const float*)d_in[4];
    const float* W1 = (const float*)d_in[5];
    const float* b1 = (const float*)d_in[6];
    const float* W2 = (const float*)d_in[7];
    const float* b2 = (const float*)d_in[8];
    float* out = (float*)d_out;

    const int N = 50000;
    const int E = in_sizes[2];          // 800000
    const int* row = ei;
    const int* col = ei + E;

    // float regions (each N*D = 6.4M floats):
    //   bufA: agg(L0) then h1        bufB: h0 then agg(L2)        bufC: agg(L1)
    // CSR: epack[E] (int2), rowptr[N+1] after the float regions.
    // CSR-build scratch aliases bufC (only written at L1, after build done).
    float* ws   = (float*)d_ws;
    size_t ND   = (size_t)N * D;
    float* bufA = ws;
    float* bufB = bufA + ND;
    float* bufC = bufB + ND;
    int2*  ep     = (int2*)(bufC + ND);
    int*   rowptr = (int*)(ep + E);

    int* cnt    = (int*)bufC;
    int* cursor = cnt + N;
    int* bsum   = cursor + N;
    int* boff   = bsum + 256;

    int nbScan = (N + 255) / 256;       // 196

    // ---- CSR build ----
    hipMemsetAsync(cnt, 0, (size_t)N * sizeof(int), stream);
    hist_kernel<<<(E + 255) / 256, 256, 0, stream>>>(row, cnt, E);
    scan1_kernel<<<nbScan, 256, 0, stream>>>(cnt, rowptr, bsum, N);
    scan2_kernel<<<1, 256, 0, stream>>>(bsum, boff, nbScan);
    scan3_kernel<<<(N + 256) / 256 + 1, 256, 0, stream>>>(rowptr, boff, cursor, N, E);
    scatter_kernel<<<(E + 255) / 256, 256, 0, stream>>>(row, col, ew, cursor, ep, E);

    int nWaves = (N + 1) / 2;
    int aggBlocks = (int)(((long long)nWaves * 64 + 255) / 256);
    int linBlocks = (N + 127) / 128;

    // layer 0: agg(x)->bufA ; linear(x,bufA)->bufB(h0)
    gather_agg<<<aggBlocks, 256, 0, stream>>>(x, rowptr, ep, bufA, N);
    sage_linear<128, true><<<linBlocks, 256, 0, stream>>>(x, bufA, W0, b0, bufB, N);

    // layer 1: agg(h0)->bufC ; linear(h0,bufC)->bufA(h1)
    gather_agg<<<aggBlocks, 256, 0, stream>>>(bufB, rowptr, ep, bufC, N);
    sage_linear<128, true><<<linBlocks, 256, 0, stream>>>(bufB, bufC, W1, b1, bufA, N);

    // layer 2: agg(h1)->bufB ; linear(h1,bufB)->out  (OUT=64, no relu)
    gather_agg<<<aggBlocks, 256, 0, stream>>>(bufA, rowptr, ep, bufB, N);
    sage_linear<64, false><<<linBlocks, 256, 0, stream>>>(bufA, bufB, W2, b2, out, N);
}

// Round 6
// 445.883 us; speedup vs baseline: 1.2155x; 1.2155x over previous
//
#include <hip/hip_runtime.h>

// GraphSAGE 3-layer, N=50000, E=800000, D=128, D_OUT=64.
// R6: bf16 feature tables + LDS-free MFMA GEMM (A/B frags loaded straight from
// global; W as hi+lo bf16 double-pass for precision), bf16 gather (half traffic).

#define D 128
#define K2 256

typedef __attribute__((ext_vector_type(8))) short short8;
typedef __attribute__((ext_vector_type(4))) float floatx4;

__device__ inline unsigned short rne_bf16(float f) {
    unsigned int u = __float_as_uint(f);
    u += 0x7fffu + ((u >> 16) & 1u);
    return (unsigned short)(u >> 16);
}

// ---------- casts ----------
__global__ void cast_x_kernel(const float* __restrict__ in, unsigned short* __restrict__ out, int n4) {
    int i = blockIdx.x * blockDim.x + threadIdx.x;
    if (i >= n4) return;
    float4 v = reinterpret_cast<const float4*>(in)[i];
    ushort4 o;
    o.x = rne_bf16(v.x); o.y = rne_bf16(v.y); o.z = rne_bf16(v.z); o.w = rne_bf16(v.w);
    reinterpret_cast<ushort4*>(out)[i] = o;
}

__global__ void cast_w_kernel(const float* __restrict__ w, unsigned short* __restrict__ hi,
                              unsigned short* __restrict__ lo, int n) {
    int i = blockIdx.x * blockDim.x + threadIdx.x;
    if (i >= n) return;
    float f = w[i];
    unsigned short h = rne_bf16(f);
    float fh = __uint_as_float(((unsigned int)h) << 16);
    hi[i] = h;
    lo[i] = rne_bf16(f - fh);
}

// ---------- CSR build ----------
__global__ void hist_kernel(const int* __restrict__ row, int* __restrict__ cnt, int E) {
    int e = blockIdx.x * blockDim.x + threadIdx.x;
    if (e < E) atomicAdd(&cnt[row[e]], 1);
}

__global__ void scan1_kernel(const int* __restrict__ cnt, int* __restrict__ rowptr,
                             int* __restrict__ bsum, int N) {
    __shared__ int s[256];
    int tid = threadIdx.x;
    int gid = blockIdx.x * 256 + tid;
    int v = (gid < N) ? cnt[gid] : 0;
    s[tid] = v;
    __syncthreads();
    for (int off = 1; off < 256; off <<= 1) {
        int t = (tid >= off) ? s[tid - off] : 0;
        __syncthreads();
        s[tid] += t;
        __syncthreads();
    }
    if (gid < N) rowptr[gid] = s[tid] - v;
    if (tid == 255) bsum[blockIdx.x] = s[255];
}

__global__ void scan2_kernel(int* __restrict__ bsum, int* __restrict__ boff, int nb) {
    __shared__ int s[256];
    int tid = threadIdx.x;
    int v = (tid < nb) ? bsum[tid] : 0;
    s[tid] = v;
    __syncthreads();
    for (int off = 1; off < 256; off <<= 1) {
        int t = (tid >= off) ? s[tid - off] : 0;
        __syncthreads();
        s[tid] += t;
        __syncthreads();
    }
    if (tid < nb) boff[tid] = s[tid] - v;
}

__global__ void scan3_kernel(int* __restrict__ rowptr, const int* __restrict__ boff,
                             int* __restrict__ cursor, int N, int E) {
    int gid = blockIdx.x * 256 + threadIdx.x;
    if (gid < N) {
        int v = rowptr[gid] + boff[gid >> 8];
        rowptr[gid] = v;
        cursor[gid] = v;
    } else if (gid == N) {
        rowptr[N] = E;
    }
}

__global__ void scatter_kernel(const int* __restrict__ row, const int* __restrict__ col,
                               const float* __restrict__ ew, int* __restrict__ cursor,
                               int2* __restrict__ ep, int E) {
    int e = blockIdx.x * blockDim.x + threadIdx.x;
    if (e >= E) return;
    int p = atomicAdd(&cursor[row[e]], 1);
    ep[p] = make_int2(col[e], __float_as_int(ew[e]));
}

// ---------- gather aggregation (bf16 source, bf16 dst) ----------
// Wave = 4 slots x 16 lanes; slot = node; lane covers 8 bf16 (16B) of the row.
// unroll 4 edges -> 16 feature loads in flight per wave. fp32 accumulate.
__device__ inline void accum8(float* acc, uint4 a, float w) {
    acc[0] += __uint_as_float(a.x << 16) * w;
    acc[1] += __uint_as_float(a.x & 0xffff0000u) * w;
    acc[2] += __uint_as_float(a.y << 16) * w;
    acc[3] += __uint_as_float(a.y & 0xffff0000u) * w;
    acc[4] += __uint_as_float(a.z << 16) * w;
    acc[5] += __uint_as_float(a.z & 0xffff0000u) * w;
    acc[6] += __uint_as_float(a.w << 16) * w;
    acc[7] += __uint_as_float(a.w & 0xffff0000u) * w;
}

__global__ void gather_agg_bf(const unsigned short* __restrict__ src, const int* __restrict__ rowptr,
                              const int2* __restrict__ ep, unsigned short* __restrict__ agg, int N) {
    long long t = (long long)blockIdx.x * blockDim.x + threadIdx.x;
    int wid = (int)(t >> 6);
    int lane = threadIdx.x & 63;
    int slot = lane >> 4;
    int fl = lane & 15;
    int n = wid * 4 + slot;
    if (n >= N) return;
    int beg = rowptr[n], end = rowptr[n + 1];
    float acc[8];
#pragma unroll
    for (int j = 0; j < 8; j++) acc[j] = 0.f;
    float ds = 0.f;
    int e = beg;
    for (; e + 3 < end; e += 4) {
        int2 p0 = ep[e], p1 = ep[e + 1], p2 = ep[e + 2], p3 = ep[e + 3];
        uint4 a0 = *reinterpret_cast<const uint4*>(src + (size_t)p0.x * D + fl * 8);
        uint4 a1 = *reinterpret_cast<const uint4*>(src + (size_t)p1.x * D + fl * 8);
        uint4 a2 = *reinterpret_cast<const uint4*>(src + (size_t)p2.x * D + fl * 8);
        uint4 a3 = *reinterpret_cast<const uint4*>(src + (size_t)p3.x * D + fl * 8);
        float w0 = __int_as_float(p0.y), w1 = __int_as_float(p1.y);
        float w2 = __int_as_float(p2.y), w3 = __int_as_float(p3.y);
        accum8(acc, a0, w0); accum8(acc, a1, w1);
        accum8(acc, a2, w2); accum8(acc, a3, w3);
        ds += w0 + w1 + w2 + w3;
    }
    for (; e < end; ++e) {
        int2 p = ep[e];
        uint4 a = *reinterpret_cast<const uint4*>(src + (size_t)p.x * D + fl * 8);
        float w = __int_as_float(p.y);
        accum8(acc, a, w);
        ds += w;
    }
    float inv = 1.0f / (ds > 1.f ? ds : 1.f);
    uint4 o;
    o.x = (unsigned int)rne_bf16(acc[0] * inv) | ((unsigned int)rne_bf16(acc[1] * inv) << 16);
    o.y = (unsigned int)rne_bf16(acc[2] * inv) | ((unsigned int)rne_bf16(acc[3] * inv) << 16);
    o.z = (unsigned int)rne_bf16(acc[4] * inv) | ((unsigned int)rne_bf16(acc[5] * inv) << 16);
    o.w = (unsigned int)rne_bf16(acc[6] * inv) | ((unsigned int)rne_bf16(acc[7] * inv) << 16);
    *reinterpret_cast<uint4*>(agg + (size_t)n * D + fl * 8) = o;
}

// ---------- MFMA GEMM: y[N,OUT] = [xhi|agghi] @ (Whi+Wlo)^T + b ----------
// One wave per 16 nodes, covering all OUT cols (NT = OUT/16 subtiles).
// A-frag: lane m=lane&15 -> node row, k=quad*8+j -> 16B contiguous global load.
// B-frag: lane n=lane&15 -> W row (output col), k contiguous -> 16B global load.
// C/D: col=lane&15, row=quad*4+reg (verified layout, m89).
template<int OUT, bool RELU, bool BF16OUT>
__global__ __launch_bounds__(256) void sage_mfma(
    const unsigned short* __restrict__ xhi, const unsigned short* __restrict__ agghi,
    const unsigned short* __restrict__ Whi, const unsigned short* __restrict__ Wlo,
    const float* __restrict__ bias, float* __restrict__ outf,
    unsigned short* __restrict__ outb, int N) {
    constexpr int NT = OUT / 16;
    int w = (blockIdx.x * 256 + threadIdx.x) >> 6;
    int m0 = w * 16;
    if (m0 >= N) return;
    int lane = threadIdx.x & 63;
    int nlane = lane & 15;
    int quad = lane >> 4;
    floatx4 acc[NT];
#pragma unroll
    for (int nt = 0; nt < NT; nt++) acc[nt] = (floatx4){0.f, 0.f, 0.f, 0.f};

    const unsigned short* arow_x = xhi + (size_t)(m0 + nlane) * D + quad * 8;
    const unsigned short* arow_g = agghi + (size_t)(m0 + nlane) * D + quad * 8;
#pragma unroll
    for (int ks = 0; ks < 8; ks++) {
        int k0 = ks * 32;
        const unsigned short* ap = (k0 < D) ? (arow_x + k0) : (arow_g + (k0 - D));
        short8 a = *reinterpret_cast<const short8*>(ap);
#pragma unroll
        for (int nt = 0; nt < NT; nt++) {
            size_t woff = (size_t)(nt * 16 + nlane) * K2 + k0 + quad * 8;
            short8 bh = *reinterpret_cast<const short8*>(Whi + woff);
            short8 bl = *reinterpret_cast<const short8*>(Wlo + woff);
            acc[nt] = __builtin_amdgcn_mfma_f32_16x16x32_bf16(a, bh, acc[nt], 0, 0, 0);
            acc[nt] = __builtin_amdgcn_mfma_f32_16x16x32_bf16(a, bl, acc[nt], 0, 0, 0);
        }
    }
#pragma unroll
    for (int nt = 0; nt < NT; nt++) {
        int c = nt * 16 + nlane;
        float bb = bias[c];
#pragma unroll
        for (int r = 0; r < 4; r++) {
            int node = m0 + quad * 4 + r;
            if (node < N) {
                float y = acc[nt][r] + bb;
                if (RELU) y = y > 0.f ? y : 0.f;
                if (BF16OUT) outb[(size_t)node * D + c] = rne_bf16(y);
                else         outf[(size_t)node * OUT + c] = y;
            }
        }
    }
}

extern "C" void kernel_launch(void* const* d_in, const int* in_sizes, int n_in,
                              void* d_out, int out_size, void* d_ws, size_t ws_size,
                              hipStream_t stream) {
    const float* x  = (const float*)d_in[0];
    const int*   ei = (const int*)d_in[1];
    const float* ew = (const float*)d_in[2];
    const float* W0 = (const float*)d_in[3];
    const float* b0 = (const float*)d_in[4];
    const float* W1 = (const float*)d_in[5];
    const float* b1 = (const float*)d_in[6];
    const float* W2 = (const float*)d_in[7];
    const float* b2 = (const float*)d_in[8];
    float* out = (float*)d_out;

    const int N = 50000;
    const int E = in_sizes[2];          // 800000
    const int* row = ei;
    const int* col = ei + E;

    // workspace layout (bytes): bf16 tables x_hi/h0_hi/h1_hi/agg_hi (12.8MB ea),
    // ep (int2, 6.4MB), rowptr, W hi/lo tables. CSR scratch aliases h0_hi
    // (h0_hi is written only by layer-0 GEMM, after CSR build completes).
    char* base = (char*)d_ws;
    size_t ND = (size_t)N * D;
    unsigned short* x_hi   = (unsigned short*)base;               base += ND * 2;
    unsigned short* h0_hi  = (unsigned short*)base;               base += ND * 2;
    unsigned short* h1_hi  = (unsigned short*)base;               base += ND * 2;
    unsigned short* agg_hi = (unsigned short*)base;               base += ND * 2;
    int2* ep               = (int2*)base;                         base += (size_t)E * 8;
    int* rowptr            = (int*)base;                          base += (size_t)(N + 1) * 4;
    unsigned short* W0hi   = (unsigned short*)base;               base += 128 * 256 * 2;
    unsigned short* W0lo   = (unsigned short*)base;               base += 128 * 256 * 2;
    unsigned short* W1hi   = (unsigned short*)base;               base += 128 * 256 * 2;
    unsigned short* W1lo   = (unsigned short*)base;               base += 128 * 256 * 2;
    unsigned short* W2hi   = (unsigned short*)base;               base += 64 * 256 * 2;
    unsigned short* W2lo   = (unsigned short*)base;               base += 64 * 256 * 2;

    int* cnt    = (int*)h0_hi;          // CSR scratch (dead until layer-0 GEMM)
    int* cursor = cnt + N;
    int* bsum   = cursor + N;
    int* boff   = bsum + 256;

    int nbScan = (N + 255) / 256;       // 196

    // ---- casts ----
    int n4 = (int)(ND / 4);
    cast_x_kernel<<<(n4 + 255) / 256, 256, 0, stream>>>(x, x_hi, n4);
    cast_w_kernel<<<(128 * 256 + 255) / 256, 256, 0, stream>>>(W0, W0hi, W0lo, 128 * 256);
    cast_w_kernel<<<(128 * 256 + 255) / 256, 256, 0, stream>>>(W1, W1hi, W1lo, 128 * 256);
    cast_w_kernel<<<(64 * 256 + 255) / 256, 256, 0, stream>>>(W2, W2hi, W2lo, 64 * 256);

    // ---- CSR build ----
    hipMemsetAsync(cnt, 0, (size_t)N * sizeof(int), stream);
    hist_kernel<<<(E + 255) / 256, 256, 0, stream>>>(row, cnt, E);
    scan1_kernel<<<nbScan, 256, 0, stream>>>(cnt, rowptr, bsum, N);
    scan2_kernel<<<1, 256, 0, stream>>>(bsum, boff, nbScan);
    scan3_kernel<<<(N + 256) / 256 + 1, 256, 0, stream>>>(rowptr, boff, cursor, N, E);
    scatter_kernel<<<(E + 255) / 256, 256, 0, stream>>>(row, col, ew, cursor, ep, E);

    int nWaves = (N + 3) / 4;                       // 12500 (4 nodes/wave)
    int aggBlocks = (int)(((long long)nWaves * 64 + 255) / 256);
    int gemmWaves = (N + 15) / 16;                  // 3125
    int gemmBlocks = (gemmWaves * 64 + 255) / 256;  // 782

    // layer 0
    gather_agg_bf<<<aggBlocks, 256, 0, stream>>>(x_hi, rowptr, ep, agg_hi, N);
    sage_mfma<128, true, true><<<gemmBlocks, 256, 0, stream>>>(
        x_hi, agg_hi, W0hi, W0lo, b0, nullptr, h0_hi, N);

    // layer 1
    gather_agg_bf<<<aggBlocks, 256, 0, stream>>>(h0_hi, rowptr, ep, agg_hi, N);
    sage_mfma<128, true, true><<<gemmBlocks, 256, 0, stream>>>(
        h0_hi, agg_hi, W1hi, W1lo, b1, nullptr, h1_hi, N);

    // layer 2 (OUT=64, no relu, fp32 out)
    gather_agg_bf<<<aggBlocks, 256, 0, stream>>>(h1_hi, rowptr, ep, agg_hi, N);
    sage_mfma<64, false, false><<<gemmBlocks, 256, 0, stream>>>(
        h1_hi, agg_hi, W2hi, W2lo, b2, out, nullptr, N);
}

// Round 7
// 342.451 us; speedup vs baseline: 1.5826x; 1.3020x over previous
//
#include <hip/hip_runtime.h>

// GraphSAGE 3-layer, N=50000, E=800000, D=128, D_OUT=64.
// R7: MFMA GEMM with LDS-staged W chunks (block = 128 nodes x 64 cols, 4 waves,
// wave = 32 nodes; W hi+lo per-32-K chunk in LDS, stride 40 shorts) +
// gather unroll x8. bf16 tables, W hi+lo error compensation (as R6).

#define D 128
#define K2 256

typedef __attribute__((ext_vector_type(8))) short short8;
typedef __attribute__((ext_vector_type(4))) float floatx4;

__device__ inline unsigned short rne_bf16(float f) {
    unsigned int u = __float_as_uint(f);
    u += 0x7fffu + ((u >> 16) & 1u);
    return (unsigned short)(u >> 16);
}

// ---------- casts ----------
__global__ void cast_x_kernel(const float* __restrict__ in, unsigned short* __restrict__ out, int n4) {
    int i = blockIdx.x * blockDim.x + threadIdx.x;
    if (i >= n4) return;
    float4 v = reinterpret_cast<const float4*>(in)[i];
    ushort4 o;
    o.x = rne_bf16(v.x); o.y = rne_bf16(v.y); o.z = rne_bf16(v.z); o.w = rne_bf16(v.w);
    reinterpret_cast<ushort4*>(out)[i] = o;
}

__global__ void cast_w_kernel(const float* __restrict__ w, unsigned short* __restrict__ hi,
                              unsigned short* __restrict__ lo, int n) {
    int i = blockIdx.x * blockDim.x + threadIdx.x;
    if (i >= n) return;
    float f = w[i];
    unsigned short h = rne_bf16(f);
    float fh = __uint_as_float(((unsigned int)h) << 16);
    hi[i] = h;
    lo[i] = rne_bf16(f - fh);
}

// ---------- CSR build ----------
__global__ void hist_kernel(const int* __restrict__ row, int* __restrict__ cnt, int E) {
    int e = blockIdx.x * blockDim.x + threadIdx.x;
    if (e < E) atomicAdd(&cnt[row[e]], 1);
}

__global__ void scan1_kernel(const int* __restrict__ cnt, int* __restrict__ rowptr,
                             int* __restrict__ bsum, int N) {
    __shared__ int s[256];
    int tid = threadIdx.x;
    int gid = blockIdx.x * 256 + tid;
    int v = (gid < N) ? cnt[gid] : 0;
    s[tid] = v;
    __syncthreads();
    for (int off = 1; off < 256; off <<= 1) {
        int t = (tid >= off) ? s[tid - off] : 0;
        __syncthreads();
        s[tid] += t;
        __syncthreads();
    }
    if (gid < N) rowptr[gid] = s[tid] - v;
    if (tid == 255) bsum[blockIdx.x] = s[255];
}

__global__ void scan2_kernel(int* __restrict__ bsum, int* __restrict__ boff, int nb) {
    __shared__ int s[256];
    int tid = threadIdx.x;
    int v = (tid < nb) ? bsum[tid] : 0;
    s[tid] = v;
    __syncthreads();
    for (int off = 1; off < 256; off <<= 1) {
        int t = (tid >= off) ? s[tid - off] : 0;
        __syncthreads();
        s[tid] += t;
        __syncthreads();
    }
    if (tid < nb) boff[tid] = s[tid] - v;
}

__global__ void scan3_kernel(int* __restrict__ rowptr, const int* __restrict__ boff,
                             int* __restrict__ cursor, int N, int E) {
    int gid = blockIdx.x * 256 + threadIdx.x;
    if (gid < N) {
        int v = rowptr[gid] + boff[gid >> 8];
        rowptr[gid] = v;
        cursor[gid] = v;
    } else if (gid == N) {
        rowptr[N] = E;
    }
}

__global__ void scatter_kernel(const int* __restrict__ row, const int* __restrict__ col,
                               const float* __restrict__ ew, int* __restrict__ cursor,
                               int2* __restrict__ ep, int E) {
    int e = blockIdx.x * blockDim.x + threadIdx.x;
    if (e >= E) return;
    int p = atomicAdd(&cursor[row[e]], 1);
    ep[p] = make_int2(col[e], __float_as_int(ew[e]));
}

// ---------- gather aggregation (bf16 src/dst), unroll x8 ----------
// Wave = 4 slots x 16 lanes; slot = node; lane covers 8 bf16 (16B).
__device__ inline void accum8(float* acc, uint4 a, float w) {
    acc[0] += __uint_as_float(a.x << 16) * w;
    acc[1] += __uint_as_float(a.x & 0xffff0000u) * w;
    acc[2] += __uint_as_float(a.y << 16) * w;
    acc[3] += __uint_as_float(a.y & 0xffff0000u) * w;
    acc[4] += __uint_as_float(a.z << 16) * w;
    acc[5] += __uint_as_float(a.z & 0xffff0000u) * w;
    acc[6] += __uint_as_float(a.w << 16) * w;
    acc[7] += __uint_as_float(a.w & 0xffff0000u) * w;
}

__global__ void gather_agg_bf(const unsigned short* __restrict__ src, const int* __restrict__ rowptr,
                              const int2* __restrict__ ep, unsigned short* __restrict__ agg, int N) {
    long long t = (long long)blockIdx.x * blockDim.x + threadIdx.x;
    int wid = (int)(t >> 6);
    int lane = threadIdx.x & 63;
    int slot = lane >> 4;
    int fl = lane & 15;
    int n = wid * 4 + slot;
    if (n >= N) return;
    int beg = rowptr[n], end = rowptr[n + 1];
    float acc[8];
#pragma unroll
    for (int j = 0; j < 8; j++) acc[j] = 0.f;
    float ds = 0.f;
    int e = beg;
    for (; e + 7 < end; e += 8) {
        int2 p[8];
#pragma unroll
        for (int u = 0; u < 8; u++) p[u] = ep[e + u];
        uint4 a[8];
#pragma unroll
        for (int u = 0; u < 8; u++)
            a[u] = *reinterpret_cast<const uint4*>(src + (size_t)p[u].x * D + fl * 8);
#pragma unroll
        for (int u = 0; u < 8; u++) {
            float w = __int_as_float(p[u].y);
            accum8(acc, a[u], w);
            ds += w;
        }
    }
    for (; e + 3 < end; e += 4) {
        int2 p[4];
#pragma unroll
        for (int u = 0; u < 4; u++) p[u] = ep[e + u];
#pragma unroll
        for (int u = 0; u < 4; u++) {
            uint4 a = *reinterpret_cast<const uint4*>(src + (size_t)p[u].x * D + fl * 8);
            float w = __int_as_float(p[u].y);
            accum8(acc, a, w);
            ds += w;
        }
    }
    for (; e < end; ++e) {
        int2 p = ep[e];
        uint4 a = *reinterpret_cast<const uint4*>(src + (size_t)p.x * D + fl * 8);
        float w = __int_as_float(p.y);
        accum8(acc, a, w);
        ds += w;
    }
    float inv = 1.0f / (ds > 1.f ? ds : 1.f);
    uint4 o;
    o.x = (unsigned int)rne_bf16(acc[0] * inv) | ((unsigned int)rne_bf16(acc[1] * inv) << 16);
    o.y = (unsigned int)rne_bf16(acc[2] * inv) | ((unsigned int)rne_bf16(acc[3] * inv) << 16);
    o.z = (unsigned int)rne_bf16(acc[4] * inv) | ((unsigned int)rne_bf16(acc[5] * inv) << 16);
    o.w = (unsigned int)rne_bf16(acc[6] * inv) | ((unsigned int)rne_bf16(acc[7] * inv) << 16);
    *reinterpret_cast<uint4*>(agg + (size_t)n * D + fl * 8) = o;
}

// ---------- MFMA GEMM with LDS-staged W ----------
// y[N, c0:c0+64] = [x|agg](bf16) @ (Whi+Wlo)[c0:c0+64,:]^T + b
// Block: 256 thr = 4 waves; wave covers 32 nodes (2 M-tiles); block 128 nodes.
// Per K-chunk (32): stage W hi+lo (64 rows x 32) into LDS (stride 40 shorts,
// 16B aligned, <=2-way banks), then 4 col-tiles x 2 M x hi/lo = 16 MFMA/wave.
// A-frag: A[m=lane&15][k=quad*8+j] -> 16B global load. C/D: col=lane&15,
// row=quad*4+reg (verified m89).
template<bool RELU, bool BF16OUT, int OSTRIDE>
__global__ __launch_bounds__(256) void sage_mfma(
    const unsigned short* __restrict__ xhi, const unsigned short* __restrict__ agghi,
    const unsigned short* __restrict__ Whi, const unsigned short* __restrict__ Wlo,
    const float* __restrict__ bias, float* __restrict__ outf,
    unsigned short* __restrict__ outb, int N) {
    constexpr int LDW = 40;
    __shared__ short lw[2][64][LDW];
    int tid = threadIdx.x;
    int wv = tid >> 6;
    int lane = tid & 63;
    int nlane = lane & 15;
    int quad = lane >> 4;
    int m0 = blockIdx.x * 128 + wv * 32;
    int c0 = blockIdx.y * 64;

    // clamped A row indices (idle lanes re-read row N-1; stores are guarded)
    int r0 = m0 + nlane;      if (r0 >= N) r0 = N - 1;
    int r1 = m0 + 16 + nlane; if (r1 >= N) r1 = N - 1;
    const unsigned short* a0x = xhi + (size_t)r0 * D + quad * 8;
    const unsigned short* a1x = xhi + (size_t)r1 * D + quad * 8;
    const unsigned short* a0g = agghi + (size_t)r0 * D + quad * 8;
    const unsigned short* a1g = agghi + (size_t)r1 * D + quad * 8;

    floatx4 acc[2][4];
#pragma unroll
    for (int mt = 0; mt < 2; mt++)
#pragma unroll
        for (int nt = 0; nt < 4; nt++) acc[mt][nt] = (floatx4){0.f, 0.f, 0.f, 0.f};

    // staging slots: tid handles s=tid and s=tid+256; which=s>>8, row=(s>>2)&63, q=s&3
    int srow = (tid >> 2) & 63;
    int sq = tid & 3;
    const unsigned short* wsrc0 = Whi + (size_t)(c0 + srow) * K2 + sq * 8;
    const unsigned short* wsrc1 = Wlo + (size_t)(c0 + srow) * K2 + sq * 8;

#pragma unroll
    for (int ks = 0; ks < 8; ks++) {
        int k0 = ks * 32;
        // A loads (global; issue before barrier)
        const unsigned short* ap0 = (k0 < D) ? (a0x + k0) : (a0g + (k0 - D));
        const unsigned short* ap1 = (k0 < D) ? (a1x + k0) : (a1g + (k0 - D));
        short8 afr0 = *reinterpret_cast<const short8*>(ap0);
        short8 afr1 = *reinterpret_cast<const short8*>(ap1);
        // stage W hi+lo chunk
        *reinterpret_cast<uint4*>(&lw[0][srow][sq * 8]) =
            *reinterpret_cast<const uint4*>(wsrc0 + k0);
        *reinterpret_cast<uint4*>(&lw[1][srow][sq * 8]) =
            *reinterpret_cast<const uint4*>(wsrc1 + k0);
        __syncthreads();
#pragma unroll
        for (int nt = 0; nt < 4; nt++) {
            short8 bh = *reinterpret_cast<const short8*>(&lw[0][nt * 16 + nlane][quad * 8]);
            short8 bl = *reinterpret_cast<const short8*>(&lw[1][nt * 16 + nlane][quad * 8]);
            acc[0][nt] = __builtin_amdgcn_mfma_f32_16x16x32_bf16(afr0, bh, acc[0][nt], 0, 0, 0);
            acc[0][nt] = __builtin_amdgcn_mfma_f32_16x16x32_bf16(afr0, bl, acc[0][nt], 0, 0, 0);
            acc[1][nt] = __builtin_amdgcn_mfma_f32_16x16x32_bf16(afr1, bh, acc[1][nt], 0, 0, 0);
            acc[1][nt] = __builtin_amdgcn_mfma_f32_16x16x32_bf16(afr1, bl, acc[1][nt], 0, 0, 0);
        }
        __syncthreads();
    }

#pragma unroll
    for (int nt = 0; nt < 4; nt++) {
        int c = c0 + nt * 16 + nlane;
        float bb = bias[c];
#pragma unroll
        for (int mt = 0; mt < 2; mt++) {
#pragma unroll
            for (int r = 0; r < 4; r++) {
                int node = m0 + mt * 16 + quad * 4 + r;
                if (node < N) {
                    float y = acc[mt][nt][r] + bb;
                    if (RELU) y = y > 0.f ? y : 0.f;
                    if (BF16OUT) outb[(size_t)node * OSTRIDE + c] = rne_bf16(y);
                    else         outf[(size_t)node * OSTRIDE + c] = y;
                }
            }
        }
    }
}

extern "C" void kernel_launch(void* const* d_in, const int* in_sizes, int n_in,
                              void* d_out, int out_size, void* d_ws, size_t ws_size,
                              hipStream_t stream) {
    const float* x  = (const float*)d_in[0];
    const int*   ei = (const int*)d_in[1];
    const float* ew = (const float*)d_in[2];
    const float* W0 = (const float*)d_in[3];
    const float* b0 = (const float*)d_in[4];
    const float* W1 = (const float*)d_in[5];
    const float* b1 = (const float*)d_in[6];
    const float* W2 = (const float*)d_in[7];
    const float* b2 = (const float*)d_in[8];
    float* out = (float*)d_out;

    const int N = 50000;
    const int E = in_sizes[2];          // 800000
    const int* row = ei;
    const int* col = ei + E;

    char* base = (char*)d_ws;
    size_t ND = (size_t)N * D;
    unsigned short* x_hi   = (unsigned short*)base;               base += ND * 2;
    unsigned short* h0_hi  = (unsigned short*)base;               base += ND * 2;
    unsigned short* h1_hi  = (unsigned short*)base;               base += ND * 2;
    unsigned short* agg_hi = (unsigned short*)base;               base += ND * 2;
    int2* ep               = (int2*)base;                         base += (size_t)E * 8;
    int* rowptr            = (int*)base;                          base += (size_t)(N + 1) * 4;
    unsigned short* W0hi   = (unsigned short*)base;               base += 128 * 256 * 2;
    unsigned short* W0lo   = (unsigned short*)base;               base += 128 * 256 * 2;
    unsigned short* W1hi   = (unsigned short*)base;               base += 128 * 256 * 2;
    unsigned short* W1lo   = (unsigned short*)base;               base += 128 * 256 * 2;
    unsigned short* W2hi   = (unsigned short*)base;               base += 64 * 256 * 2;
    unsigned short* W2lo   = (unsigned short*)base;               base += 64 * 256 * 2;

    int* cnt    = (int*)h0_hi;          // CSR scratch (dead until layer-0 GEMM)
    int* cursor = cnt + N;
    int* bsum   = cursor + N;
    int* boff   = bsum + 256;

    int nbScan = (N + 255) / 256;       // 196

    // ---- casts ----
    int n4 = (int)(ND / 4);
    cast_x_kernel<<<(n4 + 255) / 256, 256, 0, stream>>>(x, x_hi, n4);
    cast_w_kernel<<<(128 * 256 + 255) / 256, 256, 0, stream>>>(W0, W0hi, W0lo, 128 * 256);
    cast_w_kernel<<<(128 * 256 + 255) / 256, 256, 0, stream>>>(W1, W1hi, W1lo, 128 * 256);
    cast_w_kernel<<<(64 * 256 + 255) / 256, 256, 0, stream>>>(W2, W2hi, W2lo, 64 * 256);

    // ---- CSR build ----
    hipMemsetAsync(cnt, 0, (size_t)N * sizeof(int), stream);
    hist_kernel<<<(E + 255) / 256, 256, 0, stream>>>(row, cnt, E);
    scan1_kernel<<<nbScan, 256, 0, stream>>>(cnt, rowptr, bsum, N);
    scan2_kernel<<<1, 256, 0, stream>>>(bsum, boff, nbScan);
    scan3_kernel<<<(N + 256) / 256 + 1, 256, 0, stream>>>(rowptr, boff, cursor, N, E);
    scatter_kernel<<<(E + 255) / 256, 256, 0, stream>>>(row, col, ew, cursor, ep, E);

    int nWaves = (N + 3) / 4;                       // 12500 (4 nodes/wave)
    int aggBlocks = (int)(((long long)nWaves * 64 + 255) / 256);
    int nodeTiles = (N + 127) / 128;                // 391
    dim3 g128(nodeTiles, 2);                        // OUT=128: two 64-col tiles
    dim3 g64(nodeTiles, 1);                         // OUT=64

    // layer 0
    gather_agg_bf<<<aggBlocks, 256, 0, stream>>>(x_hi, rowptr, ep, agg_hi, N);
    sage_mfma<true, true, D><<<g128, 256, 0, stream>>>(
        x_hi, agg_hi, W0hi, W0lo, b0, nullptr, h0_hi, N);

    // layer 1
    gather_agg_bf<<<aggBlocks, 256, 0, stream>>>(h0_hi, rowptr, ep, agg_hi, N);
    sage_mfma<true, true, D><<<g128, 256, 0, stream>>>(
        h0_hi, agg_hi, W1hi, W1lo, b1, nullptr, h1_hi, N);

    // layer 2 (OUT=64, no relu, fp32 out)
    gather_agg_bf<<<aggBlocks, 256, 0, stream>>>(h1_hi, rowptr, ep, agg_hi, N);
    sage_mfma<false, false, 64><<<g64, 256, 0, stream>>>(
        h1_hi, agg_hi, W2hi, W2lo, b2, out, nullptr, N);
}